// Round 1
// baseline (20355.212 us; speedup 1.0000x reference)
//
#include <hip/hip_runtime.h>
#include <math.h>

namespace {
constexpr int kB   = 8192;
constexpr int kNP  = 20;
constexpr int kOBS = 17;
constexpr int kACT = 6;
constexpr int kDIN = 23;   // OBS + ACT
constexpr int kH   = 256;
constexpr int kN   = kB * kNP;
constexpr int kBR  = 16;   // rows per block in score kernel
constexpr float kLR  = 0.05f;
constexpr float kGAM = (float)(1.0 / (1e-8 + 8.0));  // 1/(1e-8 + 2*2^2)
}

// ---------------- init: gather a0, zero logp, cache sum(a0^2) ----------------
__global__ __launch_bounds__(256) void init_kernel(
    const float* __restrict__ a0_table, const int* __restrict__ idx,
    float* __restrict__ a_buf, float* __restrict__ logp_buf,
    float* __restrict__ a0sq_buf)
{
  int n = blockIdx.x * blockDim.x + threadIdx.x;
  if (n >= kN) return;
  int id = idx[n];
  const float* src = a0_table + (size_t)id * kACT;
  float s = 0.f;
  #pragma unroll
  for (int d = 0; d < kACT; ++d) {
    float v = src[d];
    a_buf[(size_t)n * kACT + d] = v;
    s += v * v;
  }
  a0sq_buf[n] = s;
  logp_buf[n] = 0.f;
}

// ---------------- W2 transpose (once per launch, tiny) ----------------
__global__ __launch_bounds__(256) void transpose_kernel(
    const float* __restrict__ W, float* __restrict__ WT)
{
  int i = blockIdx.x * blockDim.x + threadIdx.x;  // 0..65535
  int c = i >> 8, k = i & 255;
  WT[i] = W[k * kH + c];   // WT[c][k] = W[k][c]
}

__device__ __forceinline__ void fma16(float acc[kBR], const float* __restrict__ src, float w) {
  const float4* p = (const float4*)src;
  float4 a = p[0], b = p[1], c = p[2], d = p[3];
  acc[0]  = fmaf(a.x, w, acc[0]);  acc[1]  = fmaf(a.y, w, acc[1]);
  acc[2]  = fmaf(a.z, w, acc[2]);  acc[3]  = fmaf(a.w, w, acc[3]);
  acc[4]  = fmaf(b.x, w, acc[4]);  acc[5]  = fmaf(b.y, w, acc[5]);
  acc[6]  = fmaf(b.z, w, acc[6]);  acc[7]  = fmaf(b.w, w, acc[7]);
  acc[8]  = fmaf(c.x, w, acc[8]);  acc[9]  = fmaf(c.y, w, acc[9]);
  acc[10] = fmaf(c.z, w, acc[10]); acc[11] = fmaf(c.w, w, acc[11]);
  acc[12] = fmaf(d.x, w, acc[12]); acc[13] = fmaf(d.y, w, acc[13]);
  acc[14] = fmaf(d.z, w, acc[14]); acc[15] = fmaf(d.w, w, acc[15]);
}

// ---------------- score = d min(Q1,Q2) / d a ----------------
__global__ __launch_bounds__(256) void score_kernel(
    const float* __restrict__ obs, const float* __restrict__ a_buf,
    const float* __restrict__ W1a, const float* __restrict__ b1a,
    const float* __restrict__ W2a, const float* __restrict__ b2a,
    const float* __restrict__ W3a, const float* __restrict__ b3a,
    const float* __restrict__ W2Ta,
    const float* __restrict__ W1b, const float* __restrict__ b1b,
    const float* __restrict__ W2b, const float* __restrict__ b2b,
    const float* __restrict__ W3b, const float* __restrict__ b3b,
    const float* __restrict__ W2Tb,
    float* __restrict__ score)
{
  __shared__ __align__(16) float xT_s[kDIN][kBR];        // x transposed [k][r]
  __shared__ __align__(16) float h1T_s[kH][kBR + 4];     // relu(h1) transposed, padded
  __shared__ __align__(16) float g_s[kH][kBR + 4];       // dq/dh2pre transposed, padded
  __shared__ float q_s[2][kBR];
  __shared__ float sc_s[2][kBR][kACT];
  __shared__ float redq_s[4][kBR];
  __shared__ float reds_s[4][kBR][kACT];

  const int tid  = threadIdx.x;
  const int wave = tid >> 6;
  const int lane = tid & 63;
  const int r0   = blockIdx.x * kBR;

  // stage x = concat(obs, a), transposed
  for (int i = tid; i < kBR * kDIN; i += 256) {
    int r = i / kDIN, c = i % kDIN;
    float v = (c < kOBS) ? obs[(size_t)(r0 + r) * kOBS + c]
                         : a_buf[(size_t)(r0 + r) * kACT + (c - kOBS)];
    xT_s[c][r] = v;
  }
  __syncthreads();

  #pragma unroll 1
  for (int net = 0; net < 2; ++net) {
    const float* W1  = net ? W1b  : W1a;
    const float* b1  = net ? b1b  : b1a;
    const float* W2  = net ? W2b  : W2a;
    const float* b2  = net ? b2b  : b2a;
    const float* W3  = net ? W3b  : W3a;
    const float* b3  = net ? b3b  : b3a;
    const float* W2T = net ? W2Tb : W2Ta;

    float acc[kBR];

    // ---- layer 1: h1 = relu(x @ W1 + b1), thread owns column tid ----
    {
      float bv = b1[tid];
      #pragma unroll
      for (int r = 0; r < kBR; ++r) acc[r] = bv;
      #pragma unroll 1
      for (int k = 0; k < kDIN; ++k) {
        float w = W1[k * kH + tid];            // coalesced
        fma16(acc, &xT_s[k][0], w);            // uniform LDS broadcast
      }
      #pragma unroll
      for (int r = 0; r < kBR; ++r) h1T_s[tid][r] = fmaxf(acc[r], 0.f);
    }
    __syncthreads();

    // ---- layer 2: h2pre = h1 @ W2 + b2 ----
    {
      float bv = b2[tid];
      #pragma unroll
      for (int r = 0; r < kBR; ++r) acc[r] = bv;
      #pragma unroll 2
      for (int k = 0; k < kH; ++k) {
        float w = W2[k * kH + tid];            // coalesced
        fma16(acc, &h1T_s[k][0], w);
      }
    }

    // ---- epilogue: q partials + dq/dh2pre into g_s ----
    float myW3 = W3[tid];
    float qpart[kBR];
    #pragma unroll
    for (int r = 0; r < kBR; ++r) {
      float pre = acc[r];
      g_s[tid][r] = (pre > 0.f) ? myW3 : 0.f;
      qpart[r] = fmaxf(pre, 0.f) * myW3;
    }
    #pragma unroll
    for (int r = 0; r < kBR; ++r) {
      float v = qpart[r];
      #pragma unroll
      for (int m = 32; m >= 1; m >>= 1) v += __shfl_xor(v, m, 64);
      if (lane == 0) redq_s[wave][r] = v;
    }
    __syncthreads();   // g_s + redq_s visible
    if (tid < kBR) {
      q_s[net][tid] = b3[0] + redq_s[0][tid] + redq_s[1][tid]
                             + redq_s[2][tid] + redq_s[3][tid];
    }

    // ---- backward: dh1pre[k=tid] = mask1 * sum_c g[c] * W2[k][c] ----
    float acc2[kBR];
    #pragma unroll
    for (int r = 0; r < kBR; ++r) acc2[r] = 0.f;
    #pragma unroll 2
    for (int c = 0; c < kH; ++c) {
      float w = W2T[c * kH + tid];             // coalesced (pre-transposed)
      fma16(acc2, &g_s[c][0], w);
    }
    {
      const float4* hp = (const float4*)&h1T_s[tid][0];
      float4 h0 = hp[0], h1v = hp[1], h2v = hp[2], h3v = hp[3];
      float hm[kBR] = {h0.x,h0.y,h0.z,h0.w, h1v.x,h1v.y,h1v.z,h1v.w,
                       h2v.x,h2v.y,h2v.z,h2v.w, h3v.x,h3v.y,h3v.z,h3v.w};
      #pragma unroll
      for (int r = 0; r < kBR; ++r) acc2[r] = (hm[r] > 0.f) ? acc2[r] : 0.f;
    }

    // ---- score_d = sum_k dh1pre[k] * W1[OBS+d][k] ----
    #pragma unroll
    for (int d = 0; d < kACT; ++d) {
      float wd = W1[(kOBS + d) * kH + tid];    // coalesced
      #pragma unroll
      for (int r = 0; r < kBR; ++r) {
        float v = acc2[r] * wd;
        #pragma unroll
        for (int m = 32; m >= 1; m >>= 1) v += __shfl_xor(v, m, 64);
        if (lane == 0) reds_s[wave][r][d] = v;
      }
    }
    __syncthreads();
    if (tid < kBR * kACT) {
      int r = tid / kACT, d = tid % kACT;
      sc_s[net][r][d] = reds_s[0][r][d] + reds_s[1][r][d]
                      + reds_s[2][r][d] + reds_s[3][r][d];
    }
    __syncthreads();   // protect h1T_s/g_s/red buffers for next net
  }

  if (tid < kBR * kACT) {
    int r = tid / kACT, d = tid % kACT;
    int sel = (q_s[0][r] <= q_s[1][r]) ? 0 : 1;  // lax.min tie rule: <= -> x branch
    score[(size_t)(r0 + r) * kACT + d] = sc_s[sel][r][d];
  }
}

// ---------------- SVGD particle update (one 32-lane group per batch b) ----------------
__global__ __launch_bounds__(256) void svgd_kernel(
    float* __restrict__ a_buf, const float* __restrict__ score,
    float* __restrict__ logp_buf)
{
  __shared__ float X_s[8 * kNP * kACT];
  __shared__ float S_s[8 * kNP * kACT];
  const int tid = threadIdx.x;
  const size_t base = (size_t)blockIdx.x * 8 * kNP * kACT;
  for (int i = tid; i < 8 * kNP * kACT; i += 256) {
    X_s[i] = a_buf[base + i];
    S_s[i] = score[base + i];
  }
  __syncthreads();
  const int g = tid >> 5, p = tid & 31;
  if (p < kNP) {
    const float* X = X_s + g * kNP * kACT;
    const float* S = S_s + g * kNP * kACT;
    float xp[kACT], phi[kACT];
    #pragma unroll
    for (int d = 0; d < kACT; ++d) { xp[d] = X[p * kACT + d]; phi[d] = 0.f; }
    float t1 = 0.f, t2 = 0.f;
    #pragma unroll 1
    for (int q = 0; q < kNP; ++q) {
      float diff[kACT], d2 = 0.f, dot = 0.f;
      #pragma unroll
      for (int d = 0; d < kACT; ++d) {
        float dd = xp[d] - X[q * kACT + d];
        diff[d] = dd; d2 += dd * dd; dot += dd * S[q * kACT + d];
      }
      float Kv = expf(-kGAM * d2);
      #pragma unroll
      for (int d = 0; d < kACT; ++d)
        phi[d] += Kv * S[q * kACT + d] + 2.f * kGAM * diff[d] * Kv;
      t1 += Kv * dot;
      t2 += 2.f * kGAM * d2 * Kv - (float)kNP * (Kv - (q == p ? 1.f : 0.f));
    }
    size_t n = (size_t)blockIdx.x * 8 * kNP + (size_t)g * kNP + p;
    float term12 = (-2.f * kGAM / (float)kNP) * (t1 + t2);
    logp_buf[n] = logp_buf[n] - kLR * term12;
    #pragma unroll
    for (int d = 0; d < kACT; ++d) {
      float na = xp[d] + kLR * (phi[d] * (1.f / (float)kNP));
      na = fminf(fmaxf(na, -1.f), 1.f);
      a_buf[n * kACT + d] = na;
    }
  }
}

// ---------------- final: tanh + logp assembly ----------------
__global__ __launch_bounds__(256) void final_kernel(
    const float* __restrict__ a_buf, const float* __restrict__ logp_buf,
    const float* __restrict__ a0sq_buf, float* __restrict__ out_a,
    float* __restrict__ out_logp)
{
  const int tid = threadIdx.x;
  const int g = tid >> 5, p = tid & 31;
  const int b = blockIdx.x * 8 + g;
  float lp = 0.f;
  if (p < kNP) {
    size_t n = (size_t)b * kNP + p;
    float lt = 0.f;
    #pragma unroll
    for (int d = 0; d < kACT; ++d) {
      float a = a_buf[n * kACT + d];
      out_a[n * kACT + d] = tanhf(a);
      lt += 2.f * (0.6931471805599453f - a - log1pf(expf(-2.f * a)));
    }
    float lpn = 1.3941240797541021f - 5.f * a0sq_buf[n];  // -3*ln(2*pi*0.1) - 0.5/0.1*sum(a0^2)
    lp = lpn + logp_buf[n] - lt;
  }
  #pragma unroll
  for (int m = 16; m >= 1; m >>= 1) lp += __shfl_xor(lp, m, 32);
  if (p == 0) out_logp[b] = lp * (1.f / (float)kNP);
}

extern "C" void kernel_launch(void* const* d_in, const int* in_sizes, int n_in,
                              void* d_out, int out_size, void* d_ws, size_t ws_size,
                              hipStream_t stream)
{
  const float* obs  = (const float*)d_in[0];
  const float* a0t  = (const float*)d_in[1];
  const float* q1W1 = (const float*)d_in[2];
  const float* q1b1 = (const float*)d_in[3];
  const float* q1W2 = (const float*)d_in[4];
  const float* q1b2 = (const float*)d_in[5];
  const float* q1W3 = (const float*)d_in[6];
  const float* q1b3 = (const float*)d_in[7];
  const float* q2W1 = (const float*)d_in[8];
  const float* q2b1 = (const float*)d_in[9];
  const float* q2W2 = (const float*)d_in[10];
  const float* q2b2 = (const float*)d_in[11];
  const float* q2W3 = (const float*)d_in[12];
  const float* q2b3 = (const float*)d_in[13];
  const int*   idx  = (const int*)d_in[14];

  float* a_buf   = (float*)d_ws;
  float* score_b = a_buf   + (size_t)kN * kACT;
  float* logp_b  = score_b + (size_t)kN * kACT;
  float* a0sq_b  = logp_b  + kN;
  float* W2Ta    = a0sq_b  + kN;
  float* W2Tb    = W2Ta    + kH * kH;

  float* out_a  = (float*)d_out;
  float* out_lp = out_a + (size_t)kN * kACT;

  init_kernel<<<(kN + 255) / 256, 256, 0, stream>>>(a0t, idx, a_buf, logp_b, a0sq_b);
  transpose_kernel<<<kH * kH / 256, 256, 0, stream>>>(q1W2, W2Ta);
  transpose_kernel<<<kH * kH / 256, 256, 0, stream>>>(q2W2, W2Tb);

  for (int t = 0; t < 10; ++t) {
    score_kernel<<<kN / kBR, 256, 0, stream>>>(obs, a_buf,
        q1W1, q1b1, q1W2, q1b2, q1W3, q1b3, W2Ta,
        q2W1, q2b1, q2W2, q2b2, q2W3, q2b3, W2Tb, score_b);
    svgd_kernel<<<kB / 8, 256, 0, stream>>>(a_buf, score_b, logp_b);
  }

  final_kernel<<<kB / 8, 256, 0, stream>>>(a_buf, logp_b, a0sq_b, out_a, out_lp);
}

// Round 2
// 2340.778 us; speedup vs baseline: 8.6959x; 8.6959x over previous
//
#include <hip/hip_runtime.h>
#include <math.h>

typedef __attribute__((ext_vector_type(8))) __bf16 bf8;
typedef __attribute__((ext_vector_type(4))) float f4;

namespace {
constexpr int kB   = 8192;
constexpr int kNP  = 20;
constexpr int kOBS = 17;
constexpr int kACT = 6;
constexpr int kDIN = 23;
constexpr int kH   = 256;
constexpr int kN   = kB * kNP;
constexpr int BM   = 64;    // rows per block (4 waves x 16 rows)
constexpr int STR  = 264;   // h1/g/dh1m LDS row stride (bf16) -> conflict-free b128
constexpr int XSTR = 40;    // x LDS row stride
constexpr float kLR  = 0.05f;
constexpr float kGAM = (float)(1.0 / (1e-8 + 8.0));
// pack layout per net (shorts): W1p[8192] | W2p[65536] | W2Tp[65536] | Wpp[4096]
constexpr int PACKN = 8192 + 65536 + 65536 + 4096;  // 143360
}

__device__ __forceinline__ short f2bf(float f) {
  unsigned u = __builtin_bit_cast(unsigned, f);
  u = (u + 0x7FFFu + ((u >> 16) & 1u)) >> 16;   // RNE
  return (short)u;
}

// ---------------- init: gather a0, zero logp, cache sum(a0^2) ----------------
__global__ __launch_bounds__(256) void init_kernel(
    const float* __restrict__ a0_table, const int* __restrict__ idx,
    float* __restrict__ a_buf, float* __restrict__ logp_buf,
    float* __restrict__ a0sq_buf)
{
  int n = blockIdx.x * blockDim.x + threadIdx.x;
  if (n >= kN) return;
  int id = idx[n];
  const float* src = a0_table + (size_t)id * kACT;
  float s = 0.f;
  #pragma unroll
  for (int d = 0; d < kACT; ++d) {
    float v = src[d];
    a_buf[(size_t)n * kACT + d] = v;
    s += v * v;
  }
  a0sq_buf[n] = s;
  logp_buf[n] = 0.f;
}

// ---------------- weight packing into MFMA B-fragment order (once) ----------------
// B-frag element j of lane l for n-tile n, k-step kk holds B[kk*32+(l>>4)*8+j][n*16+(l&15)]
__global__ __launch_bounds__(256) void pack_kernel(
    const float* __restrict__ W1, const float* __restrict__ W2,
    short* __restrict__ out)
{
  int i = blockIdx.x * blockDim.x + threadIdx.x;
  if (i >= PACKN) return;
  float v;
  if (i < 8192) {                       // W1 pack: K=32 (padded from 23), N=256
    int t = i;
    int j = t & 7, l = (t >> 3) & 63, n = t >> 9;
    int k = ((l >> 4) << 3) + j, c = (n << 4) + (l & 15);
    v = (k < kDIN) ? W1[k * kH + c] : 0.f;
  } else if (i < 8192 + 65536) {        // W2 pack: B[k][c] = W2[k][c]
    int t = i - 8192;
    int j = t & 7, l = (t >> 3) & 63, nk = t >> 9;
    int n = nk & 15, kk = nk >> 4;
    int k = (kk << 5) + ((l >> 4) << 3) + j, c = (n << 4) + (l & 15);
    v = W2[k * kH + c];
  } else if (i < 8192 + 2 * 65536) {    // W2T pack: B[k][c] = W2[c][k]
    int t = i - 8192 - 65536;
    int j = t & 7, l = (t >> 3) & 63, nk = t >> 9;
    int n = nk & 15, kk = nk >> 4;
    int k = (kk << 5) + ((l >> 4) << 3) + j, c = (n << 4) + (l & 15);
    v = W2[c * kH + k];
  } else {                              // proj pack: B[k][d] = W1[17+d][k], d<6
    int t = i - 8192 - 2 * 65536;
    int j = t & 7, l = (t >> 3) & 63, kk = t >> 9;
    int k = (kk << 5) + ((l >> 4) << 3) + j, d = l & 15;
    v = (d < kACT) ? W1[(kOBS + d) * kH + k] : 0.f;
  }
  out[i] = f2bf(v);
}

// ---------------- score = d min(Q1,Q2) / d a  (bf16 MFMA, barrier-free) ----------------
__global__ __launch_bounds__(256) void score_mfma(
    const float* __restrict__ obs, const float* __restrict__ a_buf,
    const short* __restrict__ pack0, const short* __restrict__ pack1,
    const float* __restrict__ b1a, const float* __restrict__ b2a,
    const float* __restrict__ W3a, const float* __restrict__ b3a,
    const float* __restrict__ b1b, const float* __restrict__ b2b,
    const float* __restrict__ W3b, const float* __restrict__ b3b,
    float* __restrict__ score)
{
  __shared__ __align__(16) __bf16 buf[BM * STR];    // h1 -> g -> dh1m (wave-private rows)
  __shared__ __align__(16) __bf16 xbuf[BM * XSTR];

  const int tid  = threadIdx.x;
  const int wave = tid >> 6, lane = tid & 63;
  const int g16  = lane >> 4, r15 = lane & 15;
  const int wrow = wave * 16;
  const size_t grow0 = (size_t)blockIdx.x * BM;

  // stage x = concat(obs, a, pad) for this wave's 16 rows (wave-private: no barrier)
  for (int i = lane; i < 16 * 32; i += 64) {
    int r = i >> 5, k = i & 31;
    size_t gr = grow0 + wrow + r;
    float v = (k < kOBS) ? obs[gr * kOBS + k]
            : ((k < kDIN) ? a_buf[gr * kACT + (k - kOBS)] : 0.f);
    xbuf[(wrow + r) * XSTR + k] = (__bf16)v;
  }

  const short* packs[2] = {pack0, pack1};
  const float* b1s[2] = {b1a, b1b};
  const float* b2s[2] = {b2a, b2b};
  const float* W3s[2] = {W3a, W3b};
  const float* b3s[2] = {b3a, b3b};

  float qv[2][4];
  f4 sfr[2];
  const f4 fz = {0.f, 0.f, 0.f, 0.f};

  #pragma unroll 1
  for (int net = 0; net < 2; ++net) {
    const short* W1p  = packs[net];
    const short* W2p  = W1p + 8192;
    const short* W2Tp = W2p + 65536;
    const short* Wpp  = W2Tp + 65536;
    const float* b1 = b1s[net]; const float* b2 = b2s[net];
    const float* W3 = W3s[net]; const float* b3 = b3s[net];

    f4 acc[16];

    // ---- layer 1: h1pre = x @ W1 (K=32 incl pad) ----
    {
      bf8 xa = *(const bf8*)&xbuf[(wrow + r15) * XSTR + g16 * 8];
      #pragma unroll
      for (int n = 0; n < 16; ++n) {
        bf8 bw = *(const bf8*)&W1p[(n * 64 + lane) * 8];
        acc[n] = __builtin_amdgcn_mfma_f32_16x16x32_bf16(xa, bw, fz, 0, 0, 0);
      }
    }
    // epilogue: +b1, relu, mask bits in regs, h1 -> LDS (C-frag: row=(l>>4)*4+rr, col=n*16+(l&15))
    unsigned m1[4] = {0u, 0u, 0u, 0u};
    #pragma unroll
    for (int n = 0; n < 16; ++n) {
      float b1v = b1[n * 16 + r15];
      #pragma unroll
      for (int rr = 0; rr < 4; ++rr) {
        float h = acc[n][rr] + b1v;
        float hv = 0.f;
        if (h > 0.f) { m1[rr] |= (1u << n); hv = h; }
        buf[(wrow + g16 * 4 + rr) * STR + n * 16 + r15] = (__bf16)hv;
      }
    }

    // ---- layer 2 fwd: h2pre = h1 @ W2 ----
    #pragma unroll
    for (int n = 0; n < 16; ++n) acc[n] = fz;
    #pragma unroll 1
    for (int kk = 0; kk < 8; ++kk) {
      bf8 af = *(const bf8*)&buf[(wrow + r15) * STR + kk * 32 + g16 * 8];
      #pragma unroll
      for (int n = 0; n < 16; ++n) {
        bf8 bw = *(const bf8*)&W2p[((kk * 16 + n) * 64 + lane) * 8];
        acc[n] = __builtin_amdgcn_mfma_f32_16x16x32_bf16(af, bw, acc[n], 0, 0, 0);
      }
    }

    // epilogue: q partial + g = (h2pre>0)*W3 -> LDS (reuse buf)
    float qacc[4] = {0.f, 0.f, 0.f, 0.f};
    #pragma unroll
    for (int n = 0; n < 16; ++n) {
      float b2v = b2[n * 16 + r15];
      float w3v = W3[n * 16 + r15];
      __bf16 w3b = (__bf16)w3v;
      #pragma unroll
      for (int rr = 0; rr < 4; ++rr) {
        float h2 = acc[n][rr] + b2v;
        bool p = h2 > 0.f;
        qacc[rr] += p ? h2 * w3v : 0.f;
        buf[(wrow + g16 * 4 + rr) * STR + n * 16 + r15] = p ? w3b : (__bf16)0.f;
      }
    }
    #pragma unroll
    for (int m = 1; m <= 8; m <<= 1) {
      #pragma unroll
      for (int rr = 0; rr < 4; ++rr) qacc[rr] += __shfl_xor(qacc[rr], m, 64);
    }
    float b3v = b3[0];
    #pragma unroll
    for (int rr = 0; rr < 4; ++rr) qv[net][rr] = qacc[rr] + b3v;

    // ---- layer 2 bwd: dh1 = g @ W2^T ----
    #pragma unroll
    for (int n = 0; n < 16; ++n) acc[n] = fz;
    #pragma unroll 1
    for (int kk = 0; kk < 8; ++kk) {
      bf8 af = *(const bf8*)&buf[(wrow + r15) * STR + kk * 32 + g16 * 8];
      #pragma unroll
      for (int n = 0; n < 16; ++n) {
        bf8 bw = *(const bf8*)&W2Tp[((kk * 16 + n) * 64 + lane) * 8];
        acc[n] = __builtin_amdgcn_mfma_f32_16x16x32_bf16(af, bw, acc[n], 0, 0, 0);
      }
    }
    // mask by relu'(h1pre) (same frag coords as fwd) and write dh1m -> LDS (reuse buf)
    #pragma unroll
    for (int n = 0; n < 16; ++n) {
      #pragma unroll
      for (int rr = 0; rr < 4; ++rr) {
        float v = ((m1[rr] >> n) & 1u) ? acc[n][rr] : 0.f;
        buf[(wrow + g16 * 4 + rr) * STR + n * 16 + r15] = (__bf16)v;
      }
    }

    // ---- projection: score16 = dh1m @ W1act (N=16, d<6 valid) ----
    f4 s = fz;
    #pragma unroll 1
    for (int kk = 0; kk < 8; ++kk) {
      bf8 af = *(const bf8*)&buf[(wrow + r15) * STR + kk * 32 + g16 * 8];
      bf8 bw = *(const bf8*)&Wpp[(kk * 64 + lane) * 8];
      s = __builtin_amdgcn_mfma_f32_16x16x32_bf16(af, bw, s, 0, 0, 0);
    }
    sfr[net] = s;
  }

  // select grad of min(q1,q2) per row, write score
  if (r15 < kACT) {
    #pragma unroll
    for (int rr = 0; rr < 4; ++rr) {
      float sv = (qv[0][rr] <= qv[1][rr]) ? sfr[0][rr] : sfr[1][rr];
      score[(grow0 + wrow + g16 * 4 + rr) * kACT + r15] = sv;
    }
  }
}

// ---------------- SVGD particle update (one 32-lane group per batch b) ----------------
__global__ __launch_bounds__(256) void svgd_kernel(
    float* __restrict__ a_buf, const float* __restrict__ score,
    float* __restrict__ logp_buf)
{
  __shared__ float X_s[8 * kNP * kACT];
  __shared__ float S_s[8 * kNP * kACT];
  const int tid = threadIdx.x;
  const size_t base = (size_t)blockIdx.x * 8 * kNP * kACT;
  for (int i = tid; i < 8 * kNP * kACT; i += 256) {
    X_s[i] = a_buf[base + i];
    S_s[i] = score[base + i];
  }
  __syncthreads();
  const int g = tid >> 5, p = tid & 31;
  if (p < kNP) {
    const float* X = X_s + g * kNP * kACT;
    const float* S = S_s + g * kNP * kACT;
    float xp[kACT], phi[kACT];
    #pragma unroll
    for (int d = 0; d < kACT; ++d) { xp[d] = X[p * kACT + d]; phi[d] = 0.f; }
    float t1 = 0.f, t2 = 0.f;
    #pragma unroll 1
    for (int q = 0; q < kNP; ++q) {
      float diff[kACT], d2 = 0.f, dot = 0.f;
      #pragma unroll
      for (int d = 0; d < kACT; ++d) {
        float dd = xp[d] - X[q * kACT + d];
        diff[d] = dd; d2 += dd * dd; dot += dd * S[q * kACT + d];
      }
      float Kv = expf(-kGAM * d2);
      #pragma unroll
      for (int d = 0; d < kACT; ++d)
        phi[d] += Kv * S[q * kACT + d] + 2.f * kGAM * diff[d] * Kv;
      t1 += Kv * dot;
      t2 += 2.f * kGAM * d2 * Kv - (float)kNP * (Kv - (q == p ? 1.f : 0.f));
    }
    size_t n = (size_t)blockIdx.x * 8 * kNP + (size_t)g * kNP + p;
    float term12 = (-2.f * kGAM / (float)kNP) * (t1 + t2);
    logp_buf[n] = logp_buf[n] - kLR * term12;
    #pragma unroll
    for (int d = 0; d < kACT; ++d) {
      float na = xp[d] + kLR * (phi[d] * (1.f / (float)kNP));
      na = fminf(fmaxf(na, -1.f), 1.f);
      a_buf[n * kACT + d] = na;
    }
  }
}

// ---------------- final: tanh + logp assembly ----------------
__global__ __launch_bounds__(256) void final_kernel(
    const float* __restrict__ a_buf, const float* __restrict__ logp_buf,
    const float* __restrict__ a0sq_buf, float* __restrict__ out_a,
    float* __restrict__ out_logp)
{
  const int tid = threadIdx.x;
  const int g = tid >> 5, p = tid & 31;
  const int b = blockIdx.x * 8 + g;
  float lp = 0.f;
  if (p < kNP) {
    size_t n = (size_t)b * kNP + p;
    float lt = 0.f;
    #pragma unroll
    for (int d = 0; d < kACT; ++d) {
      float a = a_buf[n * kACT + d];
      out_a[n * kACT + d] = tanhf(a);
      lt += 2.f * (0.6931471805599453f - a - log1pf(expf(-2.f * a)));
    }
    float lpn = 1.3941240797541021f - 5.f * a0sq_buf[n];
    lp = lpn + logp_buf[n] - lt;
  }
  #pragma unroll
  for (int m = 16; m >= 1; m >>= 1) lp += __shfl_xor(lp, m, 32);
  if (p == 0) out_logp[b] = lp * (1.f / (float)kNP);
}

extern "C" void kernel_launch(void* const* d_in, const int* in_sizes, int n_in,
                              void* d_out, int out_size, void* d_ws, size_t ws_size,
                              hipStream_t stream)
{
  const float* obs  = (const float*)d_in[0];
  const float* a0t  = (const float*)d_in[1];
  const float* q1W1 = (const float*)d_in[2];
  const float* q1b1 = (const float*)d_in[3];
  const float* q1W2 = (const float*)d_in[4];
  const float* q1b2 = (const float*)d_in[5];
  const float* q1W3 = (const float*)d_in[6];
  const float* q1b3 = (const float*)d_in[7];
  const float* q2W1 = (const float*)d_in[8];
  const float* q2b1 = (const float*)d_in[9];
  const float* q2W2 = (const float*)d_in[10];
  const float* q2b2 = (const float*)d_in[11];
  const float* q2W3 = (const float*)d_in[12];
  const float* q2b3 = (const float*)d_in[13];
  const int*   idx  = (const int*)d_in[14];

  float* a_buf   = (float*)d_ws;
  float* score_b = a_buf   + (size_t)kN * kACT;
  float* logp_b  = score_b + (size_t)kN * kACT;
  float* a0sq_b  = logp_b  + kN;
  short* pack0   = (short*)(a0sq_b + kN);
  short* pack1   = pack0 + PACKN;

  float* out_a  = (float*)d_out;
  float* out_lp = out_a + (size_t)kN * kACT;

  init_kernel<<<(kN + 255) / 256, 256, 0, stream>>>(a0t, idx, a_buf, logp_b, a0sq_b);
  pack_kernel<<<(PACKN + 255) / 256, 256, 0, stream>>>(q1W1, q1W2, pack0);
  pack_kernel<<<(PACKN + 255) / 256, 256, 0, stream>>>(q2W1, q2W2, pack1);

  for (int t = 0; t < 10; ++t) {
    score_mfma<<<kN / BM, 256, 0, stream>>>(obs, a_buf, pack0, pack1,
        q1b1, q1b2, q1W3, q1b3, q2b1, q2b2, q2W3, q2b3, score_b);
    svgd_kernel<<<kB / 8, 256, 0, stream>>>(a_buf, score_b, logp_b);
  }

  final_kernel<<<kB / 8, 256, 0, stream>>>(a_buf, logp_b, a0sq_b, out_a, out_lp);
}

// Round 3
// 1926.694 us; speedup vs baseline: 10.5648x; 1.2149x over previous
//
#include <hip/hip_runtime.h>
#include <math.h>

typedef __attribute__((ext_vector_type(8))) __bf16 bf8;
typedef __attribute__((ext_vector_type(4))) float f4;

namespace {
constexpr int kB   = 8192;
constexpr int kNP  = 20;
constexpr int kOBS = 17;
constexpr int kACT = 6;
constexpr int kDIN = 23;
constexpr int kH   = 256;
constexpr int kN   = kB * kNP;
constexpr int BM   = 64;    // rows per block; waves split the 256 cols (4 n-tiles each)
constexpr int STR  = 264;   // h1/g/dh1m LDS row stride (bf16) -> 2-way (free) on b128 reads
constexpr int XSTR = 40;    // x LDS row stride
constexpr float kLR  = 0.05f;
constexpr float kGAM = (float)(1.0 / (1e-8 + 8.0));
// pack layout per net (shorts): W1p[8192] | W2p[65536] | W2Tp[65536] | Wpp[4096]
constexpr int PACKN = 8192 + 65536 + 65536 + 4096;  // 143360
}

__device__ __forceinline__ short f2bf(float f) {
  unsigned u = __builtin_bit_cast(unsigned, f);
  u = (u + 0x7FFFu + ((u >> 16) & 1u)) >> 16;   // RNE
  return (short)u;
}

// ---------------- init: gather a0, zero logp, cache sum(a0^2) ----------------
__global__ __launch_bounds__(256) void init_kernel(
    const float* __restrict__ a0_table, const int* __restrict__ idx,
    float* __restrict__ a_buf, float* __restrict__ logp_buf,
    float* __restrict__ a0sq_buf)
{
  int n = blockIdx.x * blockDim.x + threadIdx.x;
  if (n >= kN) return;
  int id = idx[n];
  const float* src = a0_table + (size_t)id * kACT;
  float s = 0.f;
  #pragma unroll
  for (int d = 0; d < kACT; ++d) {
    float v = src[d];
    a_buf[(size_t)n * kACT + d] = v;
    s += v * v;
  }
  a0sq_buf[n] = s;
  logp_buf[n] = 0.f;
}

// ---------------- weight packing into MFMA B-fragment order (once) ----------------
// B-frag element j of lane l for n-tile n, k-step kk holds B[kk*32+(l>>4)*8+j][n*16+(l&15)]
__global__ __launch_bounds__(256) void pack_kernel(
    const float* __restrict__ W1, const float* __restrict__ W2,
    short* __restrict__ out)
{
  int i = blockIdx.x * blockDim.x + threadIdx.x;
  if (i >= PACKN) return;
  float v;
  if (i < 8192) {                       // W1 pack: K=32 (padded from 23), N=256
    int t = i;
    int j = t & 7, l = (t >> 3) & 63, n = t >> 9;
    int k = ((l >> 4) << 3) + j, c = (n << 4) + (l & 15);
    v = (k < kDIN) ? W1[k * kH + c] : 0.f;
  } else if (i < 8192 + 65536) {        // W2 pack: B[k][c] = W2[k][c]
    int t = i - 8192;
    int j = t & 7, l = (t >> 3) & 63, nk = t >> 9;
    int n = nk & 15, kk = nk >> 4;
    int k = (kk << 5) + ((l >> 4) << 3) + j, c = (n << 4) + (l & 15);
    v = W2[k * kH + c];
  } else if (i < 8192 + 2 * 65536) {    // W2T pack: B[k][c] = W2[c][k]
    int t = i - 8192 - 65536;
    int j = t & 7, l = (t >> 3) & 63, nk = t >> 9;
    int n = nk & 15, kk = nk >> 4;
    int k = (kk << 5) + ((l >> 4) << 3) + j, c = (n << 4) + (l & 15);
    v = W2[c * kH + k];
  } else {                              // proj pack: B[k][d] = W1[17+d][k], d<6
    int t = i - 8192 - 2 * 65536;
    int j = t & 7, l = (t >> 3) & 63, kk = t >> 9;
    int k = (kk << 5) + ((l >> 4) << 3) + j, d = l & 15;
    v = (d < kACT) ? W1[(kOBS + d) * kH + k] : 0.f;
  }
  out[i] = f2bf(v);
}

// ---------------- score = d min(Q1,Q2) / d a  (bf16 MFMA, col-split GEMM) ----------------
__global__ __launch_bounds__(256) void score_mfma(
    const float* __restrict__ obs, const float* __restrict__ a_buf,
    const short* __restrict__ pack0, const short* __restrict__ pack1,
    const float* __restrict__ b1a, const float* __restrict__ b2a,
    const float* __restrict__ W3a, const float* __restrict__ b3a,
    const float* __restrict__ b1b, const float* __restrict__ b2b,
    const float* __restrict__ W3b, const float* __restrict__ b3b,
    float* __restrict__ score)
{
  __shared__ __align__(16) __bf16 hbuf[BM * STR];   // h1 -> g -> dh1m (cross-wave)
  __shared__ __align__(16) __bf16 xbuf[BM * XSTR];
  __shared__ float qred[4][BM];
  __shared__ float qv_s[2][BM];

  const int tid  = threadIdx.x;
  const int wave = tid >> 6, lane = tid & 63;
  const int g16  = lane >> 4, r15 = lane & 15;
  const size_t grow0 = (size_t)blockIdx.x * BM;

  // stage x = concat(obs, a, pad) for all 64 rows
  for (int i = tid; i < BM * 32; i += 256) {
    int r = i >> 5, k = i & 31;
    size_t gr = grow0 + r;
    float v = (k < kOBS) ? obs[gr * kOBS + k]
            : ((k < kDIN) ? a_buf[gr * kACT + (k - kOBS)] : 0.f);
    xbuf[r * XSTR + k] = (__bf16)v;
  }
  __syncthreads();

  const short* packs[2] = {pack0, pack1};
  const float* b1s[2] = {b1a, b1b};
  const float* b2s[2] = {b2a, b2b};
  const float* W3s[2] = {W3a, W3b};
  const float* b3s[2] = {b3a, b3b};

  f4 sfr[2];
  const f4 fz = {0.f, 0.f, 0.f, 0.f};

  #pragma unroll 1
  for (int net = 0; net < 2; ++net) {
    const short* W1p  = packs[net];
    const short* W2p  = W1p + 8192;
    const short* W2Tp = W2p + 65536;
    const short* Wpp  = W2Tp + 65536;
    const float* b1 = b1s[net]; const float* b2 = b2s[net];
    const float* W3 = W3s[net]; const float* b3 = b3s[net];

    f4 acc[4][4];    // [Mtile][ntile]

    // ---- layer 1: h1pre = x @ W1, this wave's 4 n-tiles, 4 M-tiles ----
    {
      float b1v[4];
      #pragma unroll
      for (int n = 0; n < 4; ++n) b1v[n] = b1[(4 * wave + n) * 16 + r15];
      bf8 xa[4];
      #pragma unroll
      for (int m = 0; m < 4; ++m)
        xa[m] = *(const bf8*)&xbuf[(m * 16 + r15) * XSTR + g16 * 8];
      #pragma unroll
      for (int n = 0; n < 4; ++n) {
        bf8 bw = *(const bf8*)&W1p[((4 * wave + n) * 64 + lane) * 8];
        #pragma unroll
        for (int m = 0; m < 4; ++m)
          acc[m][n] = __builtin_amdgcn_mfma_f32_16x16x32_bf16(xa[m], bw, fz, 0, 0, 0);
      }
      // epilogue: +b1, relu, mask bits, h1 -> LDS
      unsigned m1l[4] = {0u, 0u, 0u, 0u};
      #pragma unroll
      for (int n = 0; n < 4; ++n) {
        #pragma unroll
        for (int m = 0; m < 4; ++m) {
          #pragma unroll
          for (int rr = 0; rr < 4; ++rr) {
            float h = acc[m][n][rr] + b1v[n];
            float hv = 0.f;
            if (h > 0.f) { m1l[m] |= (1u << (n * 4 + rr)); hv = h; }
            hbuf[(m * 16 + g16 * 4 + rr) * STR + (4 * wave + n) * 16 + r15] = (__bf16)hv;
          }
        }
      }
      __syncthreads();

      // ---- layer 2 fwd: h2pre = h1 @ W2 ----
      float b2v[4], w3v[4];
      #pragma unroll
      for (int n = 0; n < 4; ++n) {
        b2v[n] = b2[(4 * wave + n) * 16 + r15];
        w3v[n] = W3[(4 * wave + n) * 16 + r15];
      }
      #pragma unroll
      for (int n = 0; n < 4; ++n)
        #pragma unroll
        for (int m = 0; m < 4; ++m) acc[m][n] = fz;
      #pragma unroll 2
      for (int kk = 0; kk < 8; ++kk) {
        bf8 af[4];
        #pragma unroll
        for (int m = 0; m < 4; ++m)
          af[m] = *(const bf8*)&hbuf[(m * 16 + r15) * STR + kk * 32 + g16 * 8];
        #pragma unroll
        for (int n = 0; n < 4; ++n) {
          bf8 bw = *(const bf8*)&W2p[((kk * 16 + 4 * wave + n) * 64 + lane) * 8];
          #pragma unroll
          for (int m = 0; m < 4; ++m)
            acc[m][n] = __builtin_amdgcn_mfma_f32_16x16x32_bf16(af[m], bw, acc[m][n], 0, 0, 0);
        }
      }
      __syncthreads();   // all waves done reading h1

      // epilogue: q partials + g -> LDS
      float qacc[4][4];
      #pragma unroll
      for (int m = 0; m < 4; ++m)
        #pragma unroll
        for (int rr = 0; rr < 4; ++rr) qacc[m][rr] = 0.f;
      #pragma unroll
      for (int n = 0; n < 4; ++n) {
        __bf16 w3b = (__bf16)w3v[n];
        #pragma unroll
        for (int m = 0; m < 4; ++m) {
          #pragma unroll
          for (int rr = 0; rr < 4; ++rr) {
            float h2 = acc[m][n][rr] + b2v[n];
            bool p = h2 > 0.f;
            qacc[m][rr] += p ? h2 * w3v[n] : 0.f;
            hbuf[(m * 16 + g16 * 4 + rr) * STR + (4 * wave + n) * 16 + r15]
                = p ? w3b : (__bf16)0.f;
          }
        }
      }
      #pragma unroll
      for (int m = 0; m < 4; ++m) {
        #pragma unroll
        for (int rr = 0; rr < 4; ++rr) {
          float v = qacc[m][rr];
          v += __shfl_xor(v, 1, 64); v += __shfl_xor(v, 2, 64);
          v += __shfl_xor(v, 4, 64); v += __shfl_xor(v, 8, 64);
          if (r15 == 0) qred[wave][m * 16 + g16 * 4 + rr] = v;
        }
      }
      __syncthreads();   // g + qred visible
      if (tid < BM)
        qv_s[net][tid] = qred[0][tid] + qred[1][tid] + qred[2][tid] + qred[3][tid] + b3[0];

      // ---- layer 2 bwd: dh1 = g @ W2^T ----
      #pragma unroll
      for (int n = 0; n < 4; ++n)
        #pragma unroll
        for (int m = 0; m < 4; ++m) acc[m][n] = fz;
      #pragma unroll 2
      for (int kk = 0; kk < 8; ++kk) {
        bf8 af[4];
        #pragma unroll
        for (int m = 0; m < 4; ++m)
          af[m] = *(const bf8*)&hbuf[(m * 16 + r15) * STR + kk * 32 + g16 * 8];
        #pragma unroll
        for (int n = 0; n < 4; ++n) {
          bf8 bw = *(const bf8*)&W2Tp[((kk * 16 + 4 * wave + n) * 64 + lane) * 8];
          #pragma unroll
          for (int m = 0; m < 4; ++m)
            acc[m][n] = __builtin_amdgcn_mfma_f32_16x16x32_bf16(af[m], bw, acc[m][n], 0, 0, 0);
        }
      }
      __syncthreads();   // all waves done reading g (and qv_s write ordered)

      // mask by relu'(h1pre), write dh1m -> LDS
      #pragma unroll
      for (int n = 0; n < 4; ++n) {
        #pragma unroll
        for (int m = 0; m < 4; ++m) {
          #pragma unroll
          for (int rr = 0; rr < 4; ++rr) {
            float v = ((m1l[m] >> (n * 4 + rr)) & 1u) ? acc[m][n][rr] : 0.f;
            hbuf[(m * 16 + g16 * 4 + rr) * STR + (4 * wave + n) * 16 + r15] = (__bf16)v;
          }
        }
      }
      __syncthreads();

      // ---- projection: wave owns M-tile == wave ----
      f4 s = fz;
      #pragma unroll
      for (int kk = 0; kk < 8; ++kk) {
        bf8 af = *(const bf8*)&hbuf[(wave * 16 + r15) * STR + kk * 32 + g16 * 8];
        bf8 bw = *(const bf8*)&Wpp[(kk * 64 + lane) * 8];
        s = __builtin_amdgcn_mfma_f32_16x16x32_bf16(af, bw, s, 0, 0, 0);
      }
      sfr[net] = s;
      __syncthreads();   // protect hbuf for next net's h1 write
    }
  }

  // select grad of min(q1,q2) per row, write score
  if (r15 < kACT) {
    #pragma unroll
    for (int rr = 0; rr < 4; ++rr) {
      int r = wave * 16 + g16 * 4 + rr;
      float sv = (qv_s[0][r] <= qv_s[1][r]) ? sfr[0][rr] : sfr[1][rr];
      score[(grow0 + r) * kACT + r15] = sv;
    }
  }
}

// ---------------- SVGD particle update (one 32-lane group per batch b) ----------------
__global__ __launch_bounds__(256) void svgd_kernel(
    float* __restrict__ a_buf, const float* __restrict__ score,
    float* __restrict__ logp_buf)
{
  __shared__ float X_s[8 * kNP * kACT];
  __shared__ float S_s[8 * kNP * kACT];
  const int tid = threadIdx.x;
  const size_t base = (size_t)blockIdx.x * 8 * kNP * kACT;
  for (int i = tid; i < 8 * kNP * kACT; i += 256) {
    X_s[i] = a_buf[base + i];
    S_s[i] = score[base + i];
  }
  __syncthreads();
  const int g = tid >> 5, p = tid & 31;
  if (p < kNP) {
    const float* X = X_s + g * kNP * kACT;
    const float* S = S_s + g * kNP * kACT;
    float xp[kACT], phi[kACT];
    #pragma unroll
    for (int d = 0; d < kACT; ++d) { xp[d] = X[p * kACT + d]; phi[d] = 0.f; }
    float t1 = 0.f, t2 = 0.f;
    #pragma unroll 1
    for (int q = 0; q < kNP; ++q) {
      float diff[kACT], d2 = 0.f, dot = 0.f;
      #pragma unroll
      for (int d = 0; d < kACT; ++d) {
        float dd = xp[d] - X[q * kACT + d];
        diff[d] = dd; d2 += dd * dd; dot += dd * S[q * kACT + d];
      }
      float Kv = expf(-kGAM * d2);
      #pragma unroll
      for (int d = 0; d < kACT; ++d)
        phi[d] += Kv * S[q * kACT + d] + 2.f * kGAM * diff[d] * Kv;
      t1 += Kv * dot;
      t2 += 2.f * kGAM * d2 * Kv - (float)kNP * (Kv - (q == p ? 1.f : 0.f));
    }
    size_t n = (size_t)blockIdx.x * 8 * kNP + (size_t)g * kNP + p;
    float term12 = (-2.f * kGAM / (float)kNP) * (t1 + t2);
    logp_buf[n] = logp_buf[n] - kLR * term12;
    #pragma unroll
    for (int d = 0; d < kACT; ++d) {
      float na = xp[d] + kLR * (phi[d] * (1.f / (float)kNP));
      na = fminf(fmaxf(na, -1.f), 1.f);
      a_buf[n * kACT + d] = na;
    }
  }
}

// ---------------- final: tanh + logp assembly ----------------
__global__ __launch_bounds__(256) void final_kernel(
    const float* __restrict__ a_buf, const float* __restrict__ logp_buf,
    const float* __restrict__ a0sq_buf, float* __restrict__ out_a,
    float* __restrict__ out_logp)
{
  const int tid = threadIdx.x;
  const int g = tid >> 5, p = tid & 31;
  const int b = blockIdx.x * 8 + g;
  float lp = 0.f;
  if (p < kNP) {
    size_t n = (size_t)b * kNP + p;
    float lt = 0.f;
    #pragma unroll
    for (int d = 0; d < kACT; ++d) {
      float a = a_buf[n * kACT + d];
      out_a[n * kACT + d] = tanhf(a);
      lt += 2.f * (0.6931471805599453f - a - log1pf(expf(-2.f * a)));
    }
    float lpn = 1.3941240797541021f - 5.f * a0sq_buf[n];
    lp = lpn + logp_buf[n] - lt;
  }
  #pragma unroll
  for (int m = 16; m >= 1; m >>= 1) lp += __shfl_xor(lp, m, 32);
  if (p == 0) out_logp[b] = lp * (1.f / (float)kNP);
}

extern "C" void kernel_launch(void* const* d_in, const int* in_sizes, int n_in,
                              void* d_out, int out_size, void* d_ws, size_t ws_size,
                              hipStream_t stream)
{
  const float* obs  = (const float*)d_in[0];
  const float* a0t  = (const float*)d_in[1];
  const float* q1W1 = (const float*)d_in[2];
  const float* q1b1 = (const float*)d_in[3];
  const float* q1W2 = (const float*)d_in[4];
  const float* q1b2 = (const float*)d_in[5];
  const float* q1W3 = (const float*)d_in[6];
  const float* q1b3 = (const float*)d_in[7];
  const float* q2W1 = (const float*)d_in[8];
  const float* q2b1 = (const float*)d_in[9];
  const float* q2W2 = (const float*)d_in[10];
  const float* q2b2 = (const float*)d_in[11];
  const float* q2W3 = (const float*)d_in[12];
  const float* q2b3 = (const float*)d_in[13];
  const int*   idx  = (const int*)d_in[14];

  float* a_buf   = (float*)d_ws;
  float* score_b = a_buf   + (size_t)kN * kACT;
  float* logp_b  = score_b + (size_t)kN * kACT;
  float* a0sq_b  = logp_b  + kN;
  short* pack0   = (short*)(a0sq_b + kN);
  short* pack1   = pack0 + PACKN;

  float* out_a  = (float*)d_out;
  float* out_lp = out_a + (size_t)kN * kACT;

  init_kernel<<<(kN + 255) / 256, 256, 0, stream>>>(a0t, idx, a_buf, logp_b, a0sq_b);
  pack_kernel<<<(PACKN + 255) / 256, 256, 0, stream>>>(q1W1, q1W2, pack0);
  pack_kernel<<<(PACKN + 255) / 256, 256, 0, stream>>>(q2W1, q2W2, pack1);

  for (int t = 0; t < 10; ++t) {
    score_mfma<<<kN / BM, 256, 0, stream>>>(obs, a_buf, pack0, pack1,
        q1b1, q1b2, q1W3, q1b3, q2b1, q2b2, q2W3, q2b3, score_b);
    svgd_kernel<<<kB / 8, 256, 0, stream>>>(a_buf, score_b, logp_b);
  }

  final_kernel<<<kB / 8, 256, 0, stream>>>(a_buf, logp_b, a0sq_b, out_a, out_lp);
}